// Round 1
// baseline (181.053 us; speedup 1.0000x reference)
//
#include <hip/hip_runtime.h>
#include <stdint.h>

typedef __attribute__((ext_vector_type(8))) short short8;
typedef __attribute__((ext_vector_type(4))) float f32x4;
typedef __attribute__((ext_vector_type(4))) unsigned short u16x4;
typedef __attribute__((ext_vector_type(8))) unsigned short u16x8;

#define AS1 __attribute__((address_space(1)))
#define AS3 __attribute__((address_space(3)))

// B=4, C=512, Lf=8192, A=6. N = 49152.
// d_out: obj [4][49152] @0, reg [4][49152][2] @196608, anchors [49152][2] @589824.
// ws layout (bytes):
//   wA    @ 0        : bf16 [512][1536], k = t*512+cin               (1,572,864)
//   hwp   @ 1572864  : bf16 [32][512], rows 0-5 obj_w, 6-17 reg_w     (32,768)
//   featT @ 1605632  : bf16 [4][8208][512], row r holds l=r-1;
//                      rows 0 and 8193 zeroed (SAME pad), 8194+ slop (33,619,968)
//   h     @ 35225600 : bf16 [4*8192][512] relu(conv) activations     (33,554,432)

__device__ __forceinline__ unsigned short f2bf(float f) {
    union { float f; unsigned int u; } v; v.f = f;
    unsigned int r = v.u + 0x7fffu + ((v.u >> 16) & 1u);
    return (unsigned short)(r >> 16);
}

__constant__ float c_AL[6] = {2.f, 4.f, 6.f, 9.f, 13.f, 18.f};

__global__ __launch_bounds__(256) void prep_kernel(
    const float* __restrict__ conv_w, const float* __restrict__ obj_w,
    const float* __restrict__ reg_w, unsigned short* __restrict__ wA,
    unsigned short* __restrict__ hwp, unsigned short* __restrict__ featT,
    float* __restrict__ anchors_out) {
    int idx = blockIdx.x * 256 + threadIdx.x;
    if (idx < 786432) {
        // wA[cout][t*512+cin] = conv_w[cout][cin][t]
        int cout = idx / 1536, rem = idx - cout * 1536;
        int t = rem >> 9, cin = rem & 511;
        wA[idx] = f2bf(conv_w[(cout * 512 + cin) * 3 + t]);
    } else if (idx < 802816) {
        int i2 = idx - 786432;
        int j = i2 >> 9, c = i2 & 511;
        float v = 0.f;
        if (j < 6) v = obj_w[j * 512 + c];
        else if (j < 18) v = reg_w[(j - 6) * 512 + c];
        hwp[i2] = f2bf(v);
    } else if (idx < 851968) {
        int n = idx - 802816;
        int l = n / 6, a = n - l * 6;
        float ctr = (float)l + 0.5f, half = 0.5f * c_AL[a];
        anchors_out[2 * n]     = ctr - half;
        anchors_out[2 * n + 1] = ctr + half;
    } else {
        int i4 = idx - 851968;
        int b = i4 >> 10, rem = i4 & 1023;
        int row = (rem >> 9) ? 8193 : 0;
        int c = rem & 511;
        featT[((size_t)b * 8208 + row) * 512 + c] = 0;
    }
}

__global__ __launch_bounds__(256) void transpose_kernel(
    const float* __restrict__ feat, unsigned short* __restrict__ featT) {
    __shared__ float tile[64][65];
    int tid = threadIdx.x;
    int l0 = blockIdx.x * 64, c0 = blockIdx.y * 64, b = blockIdx.z;
    const float* fb = feat + ((size_t)b * 512 + c0) * 8192 + l0;
    #pragma unroll
    for (int it = 0; it < 16; ++it) {
        int slot = it * 256 + tid;
        int c = slot >> 6, l = slot & 63;
        tile[c][l] = fb[(size_t)c * 8192 + l];
    }
    __syncthreads();
    unsigned short* ftb = featT + ((size_t)b * 8208 + 1 + l0) * 512 + c0;
    #pragma unroll
    for (int it = 0; it < 16; ++it) {
        int slot = it * 256 + tid;
        int l = slot >> 6, c = slot & 63;
        ftb[(size_t)l * 512 + c] = f2bf(tile[c][l]);
    }
}

// Conv GEMM: per block, 128 couts x 128 l's, K = 3 taps * 512 cin.
// 4 waves in 2x2, each wave 64x64 via 4x4 frags of 16x16x32 bf16 MFMA.
__global__ __launch_bounds__(256, 2) void conv_gemm_kernel(
    const unsigned short* __restrict__ wA,
    const unsigned short* __restrict__ featT,
    const float* __restrict__ conv_b,
    unsigned short* __restrict__ h) {
    __shared__ unsigned short smem[17408];  // 34816 B
    unsigned short* At = smem;              // [3][128][32] = 12288 hw
    unsigned short* Bt = smem + 12288;      // [144][32]    = 4608 hw

    const int tid = threadIdx.x;
    const int wave = tid >> 6, lane = tid & 63;
    const int lq = lane >> 4, lr = lane & 15;
    const int l0 = blockIdx.x * 128;
    const int m0 = blockIdx.y * 128;
    const int b = blockIdx.z;
    const int wm = wave >> 1, wn = wave & 1;
    const unsigned short* ftb = featT + (size_t)b * 8208 * 512;
    const int grow = lane >> 2;        // row within 16-row chunk
    const int gcol = (lane & 3) * 8;   // k offset (elems)

    f32x4 acc[4][4];
    #pragma unroll
    for (int i = 0; i < 4; ++i)
        #pragma unroll
        for (int j = 0; j < 4; ++j)
            acc[i][j] = (f32x4){0.f, 0.f, 0.f, 0.f};

    for (int kc = 0; kc < 16; ++kc) {
        __syncthreads();
        // 33 chunks of 1024B: 24 A-chunks ([t][16 rows]) + 9 B-chunks (144 rows)
        for (int ci = wave; ci < 33; ci += 4) {
            const unsigned short* g;
            if (ci < 24) {
                int t = ci >> 3, rb = ci & 7;
                g = wA + (size_t)(m0 + rb * 16 + grow) * 1536 + t * 512 + kc * 32 + gcol;
            } else {
                int cb = ci - 24;
                // Bt row n holds featT row l0+n  (output l = l0+n-1+... tap-shifted)
                g = ftb + (size_t)(l0 + cb * 16 + grow) * 512 + kc * 32 + gcol;
            }
            __builtin_amdgcn_global_load_lds((const AS1 void*)g,
                                             (AS3 void*)(smem + ci * 512), 16, 0, 0);
        }
        __syncthreads();
        #pragma unroll
        for (int t = 0; t < 3; ++t) {
            short8 af[4], bf[4];
            #pragma unroll
            for (int fm = 0; fm < 4; ++fm)
                af[fm] = *(const short8*)(At + (t * 128 + wm * 64 + fm * 16 + lr) * 32 + lq * 8);
            #pragma unroll
            for (int fn = 0; fn < 4; ++fn)
                bf[fn] = *(const short8*)(Bt + (wn * 64 + fn * 16 + lr + t) * 32 + lq * 8);
            #pragma unroll
            for (int fm = 0; fm < 4; ++fm)
                #pragma unroll
                for (int fn = 0; fn < 4; ++fn)
                    acc[fm][fn] = __builtin_amdgcn_mfma_f32_16x16x32_bf16(
                        af[fm], bf[fn], acc[fm][fn], 0, 0, 0);
        }
    }
    __syncthreads();
    // epilogue: bias + relu -> bf16, transpose through LDS (row stride 136)
    #pragma unroll
    for (int fm = 0; fm < 4; ++fm) {
        int mb = wm * 64 + fm * 16 + lq * 4;
        float cb0 = conv_b[m0 + mb];
        float cb1 = conv_b[m0 + mb + 1];
        float cb2 = conv_b[m0 + mb + 2];
        float cb3 = conv_b[m0 + mb + 3];
        #pragma unroll
        for (int fn = 0; fn < 4; ++fn) {
            int n = wn * 64 + fn * 16 + lr;
            f32x4 v = acc[fm][fn];
            u16x4 pk;
            pk.x = f2bf(fmaxf(v.x + cb0, 0.f));
            pk.y = f2bf(fmaxf(v.y + cb1, 0.f));
            pk.z = f2bf(fmaxf(v.z + cb2, 0.f));
            pk.w = f2bf(fmaxf(v.w + cb3, 0.f));
            *(u16x4*)(smem + n * 136 + mb) = pk;
        }
    }
    __syncthreads();
    unsigned short* hb = h + (((size_t)b * 8192 + l0) * 512) + m0;
    #pragma unroll
    for (int it = 0; it < 8; ++it) {
        int slot = it * 256 + tid;
        int n = slot >> 4, c16 = slot & 15;
        u16x8 val = *(const u16x8*)(smem + n * 136 + c16 * 8);
        *(u16x8*)(hb + (size_t)n * 512 + c16 * 8) = val;
    }
}

// Heads: out[l][j] = sum_c h[l][c] * hwp[j][c]; M=l (64/wave), N=32 (18 used), K=512.
__global__ __launch_bounds__(64) void heads_kernel(
    const unsigned short* __restrict__ h,
    const unsigned short* __restrict__ hwp,
    const float* __restrict__ obj_b,
    const float* __restrict__ reg_b,
    float* __restrict__ out) {
    int lane = threadIdx.x;
    int lq = lane >> 4, lr = lane & 15;
    int lw = blockIdx.x * 64;
    f32x4 acc[4][2];
    #pragma unroll
    for (int i = 0; i < 4; ++i) {
        acc[i][0] = (f32x4){0.f, 0.f, 0.f, 0.f};
        acc[i][1] = (f32x4){0.f, 0.f, 0.f, 0.f};
    }
    for (int kk = 0; kk < 16; ++kk) {
        short8 af[4], bf[2];
        #pragma unroll
        for (int fm = 0; fm < 4; ++fm)
            af[fm] = *(const short8*)(h + (size_t)(lw + fm * 16 + lr) * 512 + kk * 32 + lq * 8);
        #pragma unroll
        for (int fn = 0; fn < 2; ++fn)
            bf[fn] = *(const short8*)(hwp + (size_t)(fn * 16 + lr) * 512 + kk * 32 + lq * 8);
        #pragma unroll
        for (int fm = 0; fm < 4; ++fm)
            #pragma unroll
            for (int fn = 0; fn < 2; ++fn)
                acc[fm][fn] = __builtin_amdgcn_mfma_f32_16x16x32_bf16(
                    af[fm], bf[fn], acc[fm][fn], 0, 0, 0);
    }
    int bidx = lw >> 13;
    int lloc = lw & 8191;
    float* outObj = out + (size_t)bidx * 49152;
    float* outReg = out + 196608 + (size_t)bidx * 98304;
    #pragma unroll
    for (int fn = 0; fn < 2; ++fn) {
        int j = fn * 16 + lr;
        float bias = 0.f;
        if (j < 6) bias = obj_b[j];
        else if (j < 18) bias = reg_b[j - 6];
        #pragma unroll
        for (int fm = 0; fm < 4; ++fm)
            #pragma unroll
            for (int r = 0; r < 4; ++r) {
                int l = lloc + fm * 16 + lq * 4 + r;
                float v = acc[fm][fn][r] + bias;
                if (j < 6) outObj[l * 6 + j] = v;
                else if (j < 18) outReg[l * 12 + (j - 6)] = v;
            }
    }
}

extern "C" void kernel_launch(void* const* d_in, const int* in_sizes, int n_in,
                              void* d_out, int out_size, void* d_ws, size_t ws_size,
                              hipStream_t stream) {
    const float* feat   = (const float*)d_in[0];
    const float* conv_w = (const float*)d_in[1];
    const float* conv_b = (const float*)d_in[2];
    const float* obj_w  = (const float*)d_in[3];
    const float* obj_b  = (const float*)d_in[4];
    const float* reg_w  = (const float*)d_in[5];
    const float* reg_b  = (const float*)d_in[6];
    float* out = (float*)d_out;
    char* ws = (char*)d_ws;
    unsigned short* wA    = (unsigned short*)(ws);
    unsigned short* hwp   = (unsigned short*)(ws + 1572864);
    unsigned short* featT = (unsigned short*)(ws + 1605632);
    unsigned short* hbuf  = (unsigned short*)(ws + 35225600);
    float* anchors = out + 589824;

    prep_kernel<<<dim3(3344), dim3(256), 0, stream>>>(conv_w, obj_w, reg_w, wA, hwp, featT, anchors);
    transpose_kernel<<<dim3(128, 8, 4), dim3(256), 0, stream>>>(feat, featT);
    conv_gemm_kernel<<<dim3(64, 4, 4), dim3(256), 0, stream>>>(wA, featT, conv_b, hbuf);
    heads_kernel<<<dim3(512), dim3(64), 0, stream>>>(hbuf, hwp, obj_b, reg_b, out);
}

// Round 2
// 176.640 us; speedup vs baseline: 1.0250x; 1.0250x over previous
//
#include <hip/hip_runtime.h>
#include <stdint.h>

typedef __attribute__((ext_vector_type(8))) short short8;
typedef __attribute__((ext_vector_type(4))) float f32x4;
typedef __attribute__((ext_vector_type(4))) float float4v;
typedef __attribute__((ext_vector_type(4))) unsigned short u16x4;
typedef __attribute__((ext_vector_type(8))) unsigned short u16x8;

#define AS1 __attribute__((address_space(1)))
#define AS3 __attribute__((address_space(3)))

// B=4, C=512, Lf=8192, A=6. N = 49152.
// d_out: obj [4][49152] @0, reg [4][49152][2] @196608, anchors [49152][2] @589824.
// ws layout (bytes):
//   wAf   @ 0        : bf16 pre-fragmented conv weights, chunk id =
//                      (cb*3+t)*16+kc, 512 elems/chunk, lane i of chunk holds
//                      A[cout=cb*16+(i&15)][cin=kc*32+(i>>4)*8 .. +8]  (1,572,864)
//   hwp   @ 1572864  : bf16 [32][512], rows 0-5 obj_w, 6-17 reg_w, rest 0 (32,768)
//   featT @ 1605632  : bf16 [4][8208][512], row r holds l=r-1;
//                      rows 0 and 8193 zeroed (SAME pad), 8194+ slop (33,619,968)

__device__ __forceinline__ unsigned short f2bf(float f) {
    union { float f; unsigned int u; } v; v.f = f;
    unsigned int r = v.u + 0x7fffu + ((v.u >> 16) & 1u);
    return (unsigned short)(r >> 16);
}

__constant__ float c_AL[6] = {2.f, 4.f, 6.f, 9.f, 13.f, 18.f};

__global__ __launch_bounds__(256) void prep_kernel(
    const float* __restrict__ conv_w, const float* __restrict__ obj_w,
    const float* __restrict__ reg_w, const float* __restrict__ obj_b,
    const float* __restrict__ reg_b, unsigned short* __restrict__ wAf,
    unsigned short* __restrict__ hwp, unsigned short* __restrict__ featT,
    float* __restrict__ out) {
    unsigned int idx = blockIdx.x * 256 + threadIdx.x;
    if (idx < 786432u) {
        // fragment-major conv weights
        unsigned int chunkid = idx >> 9;            // 0..1535
        unsigned int within = idx & 511u;
        unsigned int lane = within >> 3, j = within & 7u;
        unsigned int kc = chunkid & 15u;
        unsigned int ct = chunkid >> 4;             // cb*3 + t
        unsigned int t = ct % 3u, cb = ct / 3u;
        unsigned int cout = cb * 16u + (lane & 15u);
        unsigned int cin = kc * 32u + (lane >> 4) * 8u + j;
        wAf[idx] = f2bf(conv_w[(cout * 512u + cin) * 3u + t]);
    } else if (idx < 802816u) {
        unsigned int i2 = idx - 786432u;
        unsigned int j = i2 >> 9, c = i2 & 511u;
        float v = 0.f;
        if (j < 6u) v = obj_w[j * 512u + c];
        else if (j < 18u) v = reg_w[(j - 6u) * 512u + c];
        hwp[i2] = f2bf(v);
    } else if (idx < 851968u) {
        unsigned int n = idx - 802816u;
        unsigned int l = n / 6u, a = n - l * 6u;
        float ctr = (float)l + 0.5f, half = 0.5f * c_AL[a];
        float* anchors = out + 589824;
        anchors[2 * n]     = ctr - half;
        anchors[2 * n + 1] = ctr + half;
    } else if (idx < 856064u) {
        unsigned int i4 = idx - 851968u;
        unsigned int b = i4 >> 10, rem = i4 & 1023u;
        unsigned int row = (rem >> 9) ? 8193u : 0u;
        unsigned int c = rem & 511u;
        featT[((size_t)b * 8208 + row) * 512 + c] = 0;
    } else if (idx < 1052672u) {
        unsigned int i = idx - 856064u;       // obj bias init: [4][8192*6]
        out[i] = obj_b[i % 6u];
    } else if (idx < 1445888u) {
        unsigned int i = idx - 1052672u;      // reg bias init: [4][8192*12]
        out[196608u + i] = reg_b[i % 12u];
    }
}

__global__ __launch_bounds__(256) void transpose_kernel(
    const float* __restrict__ feat, unsigned short* __restrict__ featT) {
    __shared__ float tileT[64][69];   // [l][c], pad 69: 2-way max on both phases
    int tid = threadIdx.x;
    int l0 = blockIdx.x * 64, c0 = blockIdx.y * 64, b = blockIdx.z;
    const float* fb = feat + ((size_t)b * 512 + c0) * 8192 + l0;
    #pragma unroll
    for (int it = 0; it < 4; ++it) {
        int slot = it * 256 + tid;
        int c = slot >> 4, l4 = (slot & 15) << 2;
        float4v v = *(const float4v*)(fb + (size_t)c * 8192 + l4);
        tileT[l4][c] = v.x; tileT[l4 + 1][c] = v.y;
        tileT[l4 + 2][c] = v.z; tileT[l4 + 3][c] = v.w;
    }
    __syncthreads();
    unsigned short* ftb = featT + ((size_t)b * 8208 + 1 + l0) * 512 + c0;
    #pragma unroll
    for (int it = 0; it < 2; ++it) {
        int slot = it * 256 + tid;
        int l = slot >> 3, c8 = (slot & 7) << 3;
        u16x8 pk;
        #pragma unroll
        for (int j = 0; j < 8; ++j) pk[j] = f2bf(tileT[l][c8 + j]);
        *(u16x8*)(ftb + (size_t)l * 512 + c8) = pk;
    }
}

// Conv GEMM: per block, 128 couts x 128 l's, K = 3 taps * 512 cin.
// Fragment-major LDS: every ds_read_b128 is base + lane*16B (conflict-free).
// Epilogue: bias+relu -> bf16 htile in LDS, then fused heads mini-GEMM
// (128 l x 32 j x 128 c) with atomicAdd partials into d_out.
__global__ __launch_bounds__(256, 3) void conv_gemm_kernel(
    const unsigned short* __restrict__ wAf,
    const unsigned short* __restrict__ featT,
    const float* __restrict__ conv_b,
    const unsigned short* __restrict__ hwp,
    float* __restrict__ out) {
    __shared__ unsigned short smem[17408];  // 34816 B: staging 33*512, htile 128*136

    const int tid = threadIdx.x;
    const int wave = tid >> 6, lane = tid & 63;
    const int lq = lane >> 4, lr = lane & 15;
    const int l0 = blockIdx.x * 128;
    const int m0 = blockIdx.y * 128;
    const int b = blockIdx.z;
    const int wm = wave >> 1, wn = wave & 1;
    const unsigned short* ftb = featT + (size_t)b * 8208 * 512;

    f32x4 acc[4][4];
    #pragma unroll
    for (int i = 0; i < 4; ++i)
        #pragma unroll
        for (int j = 0; j < 4; ++j)
            acc[i][j] = (f32x4){0.f, 0.f, 0.f, 0.f};

    for (int kc = 0; kc < 16; ++kc) {
        __syncthreads();
        // 33 chunks of 1024B: 24 A-chunks (t, 16-row blocks) + 9 B-chunks
        for (int ci = wave; ci < 33; ci += 4) {
            const unsigned short* g;
            if (ci < 24) {
                int t = ci >> 3, rb = ci & 7;
                g = wAf + ((size_t)(((m0 >> 4) + rb) * 3 + t) * 16 + kc) * 512 + lane * 8;
            } else {
                int lb = ci - 24;
                g = ftb + (size_t)(l0 + lb * 16 + lr) * 512 + kc * 32 + lq * 8;
            }
            __builtin_amdgcn_global_load_lds((const AS1 void*)g,
                                             (AS3 void*)(smem + ci * 512), 16, 0, 0);
        }
        __syncthreads();
        #pragma unroll
        for (int t = 0; t < 3; ++t) {
            short8 af[4], bf[4];
            #pragma unroll
            for (int fm = 0; fm < 4; ++fm)
                af[fm] = *(const short8*)(smem + ((t * 8 + wm * 4 + fm) << 9) + (lane << 3));
            #pragma unroll
            for (int fn = 0; fn < 4; ++fn) {
                int R = wn * 64 + fn * 16 + lr + t;   // tap-shifted B row
                bf[fn] = *(const short8*)(smem + ((24 + (R >> 4)) << 9) +
                                          ((((lq << 4) | (R & 15))) << 3));
            }
            #pragma unroll
            for (int fm = 0; fm < 4; ++fm)
                #pragma unroll
                for (int fn = 0; fn < 4; ++fn)
                    acc[fm][fn] = __builtin_amdgcn_mfma_f32_16x16x32_bf16(
                        af[fm], bf[fn], acc[fm][fn], 0, 0, 0);
        }
    }
    __syncthreads();
    // epilogue 1: bias + relu -> bf16 htile [l=n][c=cout], row stride 136
    #pragma unroll
    for (int fm = 0; fm < 4; ++fm) {
        int mb = wm * 64 + fm * 16 + lq * 4;
        float cb0 = conv_b[m0 + mb];
        float cb1 = conv_b[m0 + mb + 1];
        float cb2 = conv_b[m0 + mb + 2];
        float cb3 = conv_b[m0 + mb + 3];
        #pragma unroll
        for (int fn = 0; fn < 4; ++fn) {
            int n = wn * 64 + fn * 16 + lr;
            f32x4 v = acc[fm][fn];
            u16x4 pk;
            pk.x = f2bf(fmaxf(v.x + cb0, 0.f));
            pk.y = f2bf(fmaxf(v.y + cb1, 0.f));
            pk.z = f2bf(fmaxf(v.z + cb2, 0.f));
            pk.w = f2bf(fmaxf(v.w + cb3, 0.f));
            *(u16x4*)(smem + n * 136 + mb) = pk;
        }
    }
    __syncthreads();
    // epilogue 2: fused heads. Per wave: 32 l's x 32 j's x K=128 local couts.
    f32x4 hacc[2][2];
    #pragma unroll
    for (int i = 0; i < 2; ++i) {
        hacc[i][0] = (f32x4){0.f, 0.f, 0.f, 0.f};
        hacc[i][1] = (f32x4){0.f, 0.f, 0.f, 0.f};
    }
    const int lbase = wave * 32;
    for (int kk = 0; kk < 4; ++kk) {
        short8 ha[2], hb2[2];
        #pragma unroll
        for (int fm2 = 0; fm2 < 2; ++fm2)
            ha[fm2] = *(const short8*)(smem + (lbase + fm2 * 16 + lr) * 136 + kk * 32 + lq * 8);
        #pragma unroll
        for (int fn = 0; fn < 2; ++fn)
            hb2[fn] = *(const short8*)(hwp + (size_t)(fn * 16 + lr) * 512 + m0 + kk * 32 + lq * 8);
        #pragma unroll
        for (int fm2 = 0; fm2 < 2; ++fm2)
            #pragma unroll
            for (int fn = 0; fn < 2; ++fn)
                hacc[fm2][fn] = __builtin_amdgcn_mfma_f32_16x16x32_bf16(
                    ha[fm2], hb2[fn], hacc[fm2][fn], 0, 0, 0);
    }
    float* outObj = out + (size_t)b * 49152;
    float* outReg = out + 196608 + (size_t)b * 98304;
    #pragma unroll
    for (int fn = 0; fn < 2; ++fn) {
        int j = fn * 16 + lr;
        if (j >= 18) continue;
        #pragma unroll
        for (int fm2 = 0; fm2 < 2; ++fm2)
            #pragma unroll
            for (int r = 0; r < 4; ++r) {
                int l = l0 + lbase + fm2 * 16 + lq * 4 + r;
                float v = hacc[fm2][fn][r];
                if (j < 6) atomicAdd(&outObj[l * 6 + j], v);
                else atomicAdd(&outReg[l * 12 + (j - 6)], v);
            }
    }
}

extern "C" void kernel_launch(void* const* d_in, const int* in_sizes, int n_in,
                              void* d_out, int out_size, void* d_ws, size_t ws_size,
                              hipStream_t stream) {
    const float* feat   = (const float*)d_in[0];
    const float* conv_w = (const float*)d_in[1];
    const float* conv_b = (const float*)d_in[2];
    const float* obj_w  = (const float*)d_in[3];
    const float* obj_b  = (const float*)d_in[4];
    const float* reg_w  = (const float*)d_in[5];
    const float* reg_b  = (const float*)d_in[6];
    float* out = (float*)d_out;
    char* ws = (char*)d_ws;
    unsigned short* wAf   = (unsigned short*)(ws);
    unsigned short* hwp   = (unsigned short*)(ws + 1572864);
    unsigned short* featT = (unsigned short*)(ws + 1605632);

    prep_kernel<<<dim3(5648), dim3(256), 0, stream>>>(conv_w, obj_w, reg_w, obj_b,
                                                      reg_b, wAf, hwp, featT, out);
    transpose_kernel<<<dim3(128, 8, 4), dim3(256), 0, stream>>>(feat, featT);
    conv_gemm_kernel<<<dim3(64, 4, 4), dim3(256), 0, stream>>>(wAf, featT, conv_b, hwp, out);
}

// Round 3
// 174.584 us; speedup vs baseline: 1.0371x; 1.0118x over previous
//
#include <hip/hip_runtime.h>
#include <stdint.h>

typedef __attribute__((ext_vector_type(8))) short short8;
typedef __attribute__((ext_vector_type(4))) float f32x4;
typedef __attribute__((ext_vector_type(4))) float float4v;
typedef __attribute__((ext_vector_type(4))) unsigned short u16x4;
typedef __attribute__((ext_vector_type(8))) unsigned short u16x8;

#define AS1 __attribute__((address_space(1)))
#define AS3 __attribute__((address_space(3)))

// B=4, C=512, Lf=8192, A=6. N = 49152.
// d_out: obj [4][49152] @0, reg [4][49152][2] @196608, anchors [49152][2] @589824.
// ws layout (bytes):
//   wAf   @ 0        : bf16 pre-fragmented conv weights, chunk id =
//                      (cb*3+t)*16+kc, 512 elems/chunk, lane i of chunk holds
//                      A[cout=cb*16+(i&15)][cin=kc*32+(i>>4)*8 .. +8]  (1,572,864)
//   hwp   @ 1572864  : bf16 [32][512], rows 0-5 obj_w, 6-17 reg_w, rest 0 (32,768)
//   featT @ 1605632  : bf16 [4][8208][512], row r holds l=r-1;
//                      rows 0 and 8193 zeroed (SAME pad), 8194+ slop (33,619,968)
//   part  @ 35225600 : fp32 [4 mblk][4 b][8192 l][18 j] head partials (9,437,184)

__device__ __forceinline__ unsigned short f2bf(float f) {
    union { float f; unsigned int u; } v; v.f = f;
    unsigned int r = v.u + 0x7fffu + ((v.u >> 16) & 1u);
    return (unsigned short)(r >> 16);
}

__constant__ float c_AL[6] = {2.f, 4.f, 6.f, 9.f, 13.f, 18.f};

__global__ __launch_bounds__(256) void prep_kernel(
    const float* __restrict__ conv_w, const float* __restrict__ obj_w,
    const float* __restrict__ reg_w, unsigned short* __restrict__ wAf,
    unsigned short* __restrict__ hwp, unsigned short* __restrict__ featT,
    float* __restrict__ out) {
    unsigned int idx = blockIdx.x * 256 + threadIdx.x;
    if (idx < 786432u) {
        // fragment-major conv weights
        unsigned int chunkid = idx >> 9;            // 0..1535
        unsigned int within = idx & 511u;
        unsigned int lane = within >> 3, j = within & 7u;
        unsigned int kc = chunkid & 15u;
        unsigned int ct = chunkid >> 4;             // cb*3 + t
        unsigned int t = ct % 3u, cb = ct / 3u;
        unsigned int cout = cb * 16u + (lane & 15u);
        unsigned int cin = kc * 32u + (lane >> 4) * 8u + j;
        wAf[idx] = f2bf(conv_w[(cout * 512u + cin) * 3u + t]);
    } else if (idx < 802816u) {
        unsigned int i2 = idx - 786432u;
        unsigned int j = i2 >> 9, c = i2 & 511u;
        float v = 0.f;
        if (j < 6u) v = obj_w[j * 512u + c];
        else if (j < 18u) v = reg_w[(j - 6u) * 512u + c];
        hwp[i2] = f2bf(v);
    } else if (idx < 851968u) {
        unsigned int n = idx - 802816u;
        unsigned int l = n / 6u, a = n - l * 6u;
        float ctr = (float)l + 0.5f, half = 0.5f * c_AL[a];
        float* anchors = out + 589824;
        anchors[2 * n]     = ctr - half;
        anchors[2 * n + 1] = ctr + half;
    } else if (idx < 856064u) {
        unsigned int i4 = idx - 851968u;
        unsigned int b = i4 >> 10, rem = i4 & 1023u;
        unsigned int row = (rem >> 9) ? 8193u : 0u;
        unsigned int c = rem & 511u;
        featT[((size_t)b * 8208 + row) * 512 + c] = 0;
    }
}

__global__ __launch_bounds__(256) void transpose_kernel(
    const float* __restrict__ feat, unsigned short* __restrict__ featT) {
    __shared__ unsigned short tile[64][68];   // bf16 [c][l], pad 68
    int tid = threadIdx.x;
    int l0 = blockIdx.x * 64, c0 = blockIdx.y * 64, b = blockIdx.z;
    const float* fb = feat + ((size_t)b * 512 + c0) * 8192 + l0;
    #pragma unroll
    for (int it = 0; it < 4; ++it) {
        int slot = it * 256 + tid;
        int c = slot >> 4, l4 = (slot & 15) << 2;
        float4v v = *(const float4v*)(fb + (size_t)c * 8192 + l4);
        u16x4 pk;
        pk.x = f2bf(v.x); pk.y = f2bf(v.y);
        pk.z = f2bf(v.z); pk.w = f2bf(v.w);
        *(u16x4*)(&tile[c][l4]) = pk;
    }
    __syncthreads();
    unsigned short* ftb = featT + ((size_t)b * 8208 + 1 + l0) * 512 + c0;
    #pragma unroll
    for (int it = 0; it < 2; ++it) {
        int slot = it * 256 + tid;
        int l = slot >> 3, c8 = (slot & 7) << 3;
        u16x8 pk;
        #pragma unroll
        for (int j = 0; j < 8; ++j) pk[j] = tile[c8 + j][l];
        *(u16x8*)(ftb + (size_t)l * 512 + c8) = pk;
    }
}

// Conv GEMM: per block, 128 couts x 128 l's, K = 3 taps * 512 cin.
// A fragments load DIRECTLY global->VGPR from pre-fragmented wAf (L2-hot,
// coalesced 1KB per b128) — halves LDS-read traffic vs staging A in LDS.
// B staged via global_load_lds (9 chunks/kc). Epilogue: bias+relu -> bf16
// htile in LDS, fused heads mini-GEMM -> per-mblock partials in ws.
__global__ __launch_bounds__(256, 3) void conv_gemm_kernel(
    const unsigned short* __restrict__ wAf,
    const unsigned short* __restrict__ featT,
    const float* __restrict__ conv_b,
    const unsigned short* __restrict__ hwp,
    float* __restrict__ part) {
    __shared__ unsigned short smem[17408];  // loop: B staging 9*512; epi: htile 128*136

    const int tid = threadIdx.x;
    const int wave = tid >> 6, lane = tid & 63;
    const int lq = lane >> 4, lr = lane & 15;
    const int l0 = blockIdx.x * 128;
    const int m0 = blockIdx.y * 128;
    const int b = blockIdx.z;
    const int wm = wave >> 1, wn = wave & 1;
    const unsigned short* ftb = featT + (size_t)b * 8208 * 512;

    f32x4 acc[4][4];
    #pragma unroll
    for (int i = 0; i < 4; ++i)
        #pragma unroll
        for (int j = 0; j < 4; ++j)
            acc[i][j] = (f32x4){0.f, 0.f, 0.f, 0.f};

    for (int kc = 0; kc < 16; ++kc) {
        __syncthreads();
        // B staging: 9 chunks of 1024B (rows l0..l0+143, 32 cins)
        for (int ci = wave; ci < 9; ci += 4) {
            const unsigned short* g =
                ftb + (size_t)(l0 + ci * 16 + lr) * 512 + kc * 32 + lq * 8;
            __builtin_amdgcn_global_load_lds((const AS1 void*)g,
                                             (AS3 void*)(smem + ci * 512), 16, 0, 0);
        }
        // A fragments: direct global loads; barrier's vmcnt(0) covers latency
        short8 af[3][4];
        #pragma unroll
        for (int t = 0; t < 3; ++t)
            #pragma unroll
            for (int fm = 0; fm < 4; ++fm)
                af[t][fm] = *(const short8*)(
                    wAf + ((size_t)(((m0 >> 4) + wm * 4 + fm) * 3 + t) * 16 + kc) * 512 + lane * 8);
        __syncthreads();
        #pragma unroll
        for (int t = 0; t < 3; ++t) {
            short8 bf[4];
            #pragma unroll
            for (int fn = 0; fn < 4; ++fn) {
                int R = wn * 64 + fn * 16 + lr + t;   // tap-shifted B row
                bf[fn] = *(const short8*)(smem + ((R >> 4) << 9) +
                                          ((((lq << 4) | (R & 15))) << 3));
            }
            #pragma unroll
            for (int fm = 0; fm < 4; ++fm)
                #pragma unroll
                for (int fn = 0; fn < 4; ++fn)
                    acc[fm][fn] = __builtin_amdgcn_mfma_f32_16x16x32_bf16(
                        af[t][fm], bf[fn], acc[fm][fn], 0, 0, 0);
        }
    }
    __syncthreads();
    // epilogue 1: bias + relu -> bf16 htile [l=n][c=cout], row stride 136
    #pragma unroll
    for (int fm = 0; fm < 4; ++fm) {
        int mb = wm * 64 + fm * 16 + lq * 4;
        float cb0 = conv_b[m0 + mb];
        float cb1 = conv_b[m0 + mb + 1];
        float cb2 = conv_b[m0 + mb + 2];
        float cb3 = conv_b[m0 + mb + 3];
        #pragma unroll
        for (int fn = 0; fn < 4; ++fn) {
            int n = wn * 64 + fn * 16 + lr;
            f32x4 v = acc[fm][fn];
            u16x4 pk;
            pk.x = f2bf(fmaxf(v.x + cb0, 0.f));
            pk.y = f2bf(fmaxf(v.y + cb1, 0.f));
            pk.z = f2bf(fmaxf(v.z + cb2, 0.f));
            pk.w = f2bf(fmaxf(v.w + cb3, 0.f));
            *(u16x4*)(smem + n * 136 + mb) = pk;
        }
    }
    __syncthreads();
    // epilogue 2: fused heads. Per wave: 32 l's x 32 j's x K=128 local couts.
    f32x4 hacc[2][2];
    #pragma unroll
    for (int i = 0; i < 2; ++i) {
        hacc[i][0] = (f32x4){0.f, 0.f, 0.f, 0.f};
        hacc[i][1] = (f32x4){0.f, 0.f, 0.f, 0.f};
    }
    const int lbase = wave * 32;
    for (int kk = 0; kk < 4; ++kk) {
        short8 ha[2], hb2[2];
        #pragma unroll
        for (int fm2 = 0; fm2 < 2; ++fm2)
            ha[fm2] = *(const short8*)(smem + (lbase + fm2 * 16 + lr) * 136 + kk * 32 + lq * 8);
        #pragma unroll
        for (int fn = 0; fn < 2; ++fn)
            hb2[fn] = *(const short8*)(hwp + (size_t)(fn * 16 + lr) * 512 + m0 + kk * 32 + lq * 8);
        #pragma unroll
        for (int fm2 = 0; fm2 < 2; ++fm2)
            #pragma unroll
            for (int fn = 0; fn < 2; ++fn)
                hacc[fm2][fn] = __builtin_amdgcn_mfma_f32_16x16x32_bf16(
                    ha[fm2], hb2[fn], hacc[fm2][fn], 0, 0, 0);
    }
    // partials store: part[mblk=by][b][l][j]
    float* pb = part + ((size_t)(blockIdx.y * 4 + b) * 8192) * 18;
    #pragma unroll
    for (int fn = 0; fn < 2; ++fn) {
        int j = fn * 16 + lr;
        if (j >= 18) continue;
        #pragma unroll
        for (int fm2 = 0; fm2 < 2; ++fm2)
            #pragma unroll
            for (int r = 0; r < 4; ++r) {
                int l = l0 + lbase + fm2 * 16 + lq * 4 + r;
                pb[(size_t)l * 18 + j] = hacc[fm2][fn][r];
            }
    }
}

__global__ __launch_bounds__(256) void reduce_kernel(
    const float* __restrict__ part, const float* __restrict__ obj_b,
    const float* __restrict__ reg_b, float* __restrict__ out) {
    unsigned int idx = blockIdx.x * 256 + threadIdx.x;
    if (idx >= 589824u) return;
    unsigned int j = idx % 18u;
    unsigned int t = idx / 18u;
    unsigned int l = t & 8191u;
    unsigned int b = t >> 13;
    float s = 0.f;
    #pragma unroll
    for (int mb = 0; mb < 4; ++mb)
        s += part[((size_t)(mb * 4 + b) * 8192 + l) * 18 + j];
    if (j < 6u) {
        s += obj_b[j];
        out[(size_t)b * 49152 + l * 6 + j] = s;
    } else {
        s += reg_b[j - 6u];
        out[196608u + (size_t)b * 98304 + l * 12 + (j - 6u)] = s;
    }
}

extern "C" void kernel_launch(void* const* d_in, const int* in_sizes, int n_in,
                              void* d_out, int out_size, void* d_ws, size_t ws_size,
                              hipStream_t stream) {
    const float* feat   = (const float*)d_in[0];
    const float* conv_w = (const float*)d_in[1];
    const float* conv_b = (const float*)d_in[2];
    const float* obj_w  = (const float*)d_in[3];
    const float* obj_b  = (const float*)d_in[4];
    const float* reg_w  = (const float*)d_in[5];
    const float* reg_b  = (const float*)d_in[6];
    float* out = (float*)d_out;
    char* ws = (char*)d_ws;
    unsigned short* wAf   = (unsigned short*)(ws);
    unsigned short* hwp   = (unsigned short*)(ws + 1572864);
    unsigned short* featT = (unsigned short*)(ws + 1605632);
    float* part           = (float*)(ws + 35225600);

    prep_kernel<<<dim3(3344), dim3(256), 0, stream>>>(conv_w, obj_w, reg_w,
                                                      wAf, hwp, featT, out);
    transpose_kernel<<<dim3(128, 8, 4), dim3(256), 0, stream>>>(feat, featT);
    conv_gemm_kernel<<<dim3(64, 4, 4), dim3(256), 0, stream>>>(wAf, featT, conv_b, hwp, part);
    reduce_kernel<<<dim3(2304), dim3(256), 0, stream>>>(part, obj_b, reg_b, out);
}

// Round 4
// 166.752 us; speedup vs baseline: 1.0858x; 1.0470x over previous
//
#include <hip/hip_runtime.h>
#include <stdint.h>

typedef __attribute__((ext_vector_type(8))) short short8;
typedef __attribute__((ext_vector_type(4))) float f32x4;
typedef __attribute__((ext_vector_type(4))) float float4v;
typedef __attribute__((ext_vector_type(4))) unsigned short u16x4;
typedef __attribute__((ext_vector_type(8))) unsigned short u16x8;

#define AS1 __attribute__((address_space(1)))
#define AS3 __attribute__((address_space(3)))

// B=4, C=512, Lf=8192, A=6. N = 49152.
// d_out: obj [4][49152] @0, reg [4][49152][2] @196608, anchors [49152][2] @589824.
// ws layout (bytes):
//   wAf   @ 0        : bf16 pre-fragmented conv weights, chunk id =
//                      (cb*3+t)*16+kc, 512 elems/chunk, lane i of chunk holds
//                      A[cout=cb*16+(i&15)][cin=kc*32+(i>>4)*8 .. +8]  (1,572,864)
//   hwp   @ 1572864  : bf16 [32][512], rows 0-5 obj_w, 6-17 reg_w, rest 0 (32,768)
//   featT @ 1605632  : bf16 [4][8208][512], row r holds l=r-1;
//                      rows 0 and 8193 zeroed (SAME pad), 8194+ slop (33,619,968)
//   part  @ 35225600 : fp32 [4 mblk][4 b][8192 l][18 j] head partials (9,437,184)

__device__ __forceinline__ unsigned short f2bf(float f) {
    union { float f; unsigned int u; } v; v.f = f;
    unsigned int r = v.u + 0x7fffu + ((v.u >> 16) & 1u);
    return (unsigned short)(r >> 16);
}

__constant__ float c_AL[6] = {2.f, 4.f, 6.f, 9.f, 13.f, 18.f};

// blocks [0,4096): 64x64 transpose tiles.  blocks [4096,7440): prep work.
__global__ __launch_bounds__(256) void prep_transpose_kernel(
    const float* __restrict__ feat, const float* __restrict__ conv_w,
    const float* __restrict__ obj_w, const float* __restrict__ reg_w,
    unsigned short* __restrict__ wAf, unsigned short* __restrict__ hwp,
    unsigned short* __restrict__ featT, float* __restrict__ out) {
    __shared__ unsigned short tile[64][68];   // bf16 [c][l], pad 68
    unsigned int bx = blockIdx.x;
    int tid = threadIdx.x;
    if (bx < 4096u) {
        int l0 = (bx & 127) * 64, c0 = ((bx >> 7) & 7) * 64, b = bx >> 10;
        const float* fb = feat + ((size_t)b * 512 + c0) * 8192 + l0;
        #pragma unroll
        for (int it = 0; it < 4; ++it) {
            int slot = it * 256 + tid;
            int c = slot >> 4, l4 = (slot & 15) << 2;
            float4v v = *(const float4v*)(fb + (size_t)c * 8192 + l4);
            u16x4 pk;
            pk.x = f2bf(v.x); pk.y = f2bf(v.y);
            pk.z = f2bf(v.z); pk.w = f2bf(v.w);
            *(u16x4*)(&tile[c][l4]) = pk;
        }
        __syncthreads();
        unsigned short* ftb = featT + ((size_t)b * 8208 + 1 + l0) * 512 + c0;
        #pragma unroll
        for (int it = 0; it < 2; ++it) {
            int slot = it * 256 + tid;
            int l = slot >> 3, c8 = (slot & 7) << 3;
            u16x8 pk;
            #pragma unroll
            for (int j = 0; j < 8; ++j) pk[j] = tile[c8 + j][l];
            *(u16x8*)(ftb + (size_t)l * 512 + c8) = pk;
        }
        return;
    }
    unsigned int idx = (bx - 4096u) * 256 + tid;
    if (idx < 786432u) {
        // fragment-major conv weights
        unsigned int chunkid = idx >> 9;            // 0..1535
        unsigned int within = idx & 511u;
        unsigned int lane = within >> 3, j = within & 7u;
        unsigned int kc = chunkid & 15u;
        unsigned int ct = chunkid >> 4;             // cb*3 + t
        unsigned int t = ct % 3u, cb = ct / 3u;
        unsigned int cout = cb * 16u + (lane & 15u);
        unsigned int cin = kc * 32u + (lane >> 4) * 8u + j;
        wAf[idx] = f2bf(conv_w[(cout * 512u + cin) * 3u + t]);
    } else if (idx < 802816u) {
        unsigned int i2 = idx - 786432u;
        unsigned int j = i2 >> 9, c = i2 & 511u;
        float v = 0.f;
        if (j < 6u) v = obj_w[j * 512u + c];
        else if (j < 18u) v = reg_w[(j - 6u) * 512u + c];
        hwp[i2] = f2bf(v);
    } else if (idx < 851968u) {
        unsigned int n = idx - 802816u;
        unsigned int l = n / 6u, a = n - l * 6u;
        float ctr = (float)l + 0.5f, half = 0.5f * c_AL[a];
        float* anchors = out + 589824;
        anchors[2 * n]     = ctr - half;
        anchors[2 * n + 1] = ctr + half;
    } else if (idx < 856064u) {
        unsigned int i4 = idx - 851968u;
        unsigned int b = i4 >> 10, rem = i4 & 1023u;
        unsigned int row = (rem >> 9) ? 8193u : 0u;
        unsigned int c = rem & 511u;
        featT[((size_t)b * 8208 + row) * 512 + c] = 0;
    }
}

// Conv GEMM: per block, 128 couts x 128 l's, K = 3 taps * 512 cin.
// Fragment-major LDS for A and B: every ds_read_b128 is base + lane*16B
// (conflict-free). Epilogue: bias+relu -> bf16 htile in LDS, fused heads
// mini-GEMM -> per-mblock partials in ws (atomic-free, reduced later).
// launch_bounds(256,4): 4 blocks/CU resident (LDS 4*34816=139KB<=160KB),
// grid 1024 = exactly 4/CU -> single round, no straggler tail.
__global__ __launch_bounds__(256, 4) void conv_gemm_kernel(
    const unsigned short* __restrict__ wAf,
    const unsigned short* __restrict__ featT,
    const float* __restrict__ conv_b,
    const unsigned short* __restrict__ hwp,
    float* __restrict__ part) {
    __shared__ unsigned short smem[17408];  // loop: 33*512 staging; epi: htile 128*136

    const int tid = threadIdx.x;
    const int wave = tid >> 6, lane = tid & 63;
    const int lq = lane >> 4, lr = lane & 15;
    const int l0 = blockIdx.x * 128;
    const int m0 = blockIdx.y * 128;
    const int b = blockIdx.z;
    const int wm = wave >> 1, wn = wave & 1;
    const unsigned short* ftb = featT + (size_t)b * 8208 * 512;

    f32x4 acc[4][4];
    #pragma unroll
    for (int i = 0; i < 4; ++i)
        #pragma unroll
        for (int j = 0; j < 4; ++j)
            acc[i][j] = (f32x4){0.f, 0.f, 0.f, 0.f};

    for (int kc = 0; kc < 16; ++kc) {
        __syncthreads();
        // 33 chunks of 1024B: 24 A-chunks (fragment-major wAf) + 9 B-chunks
        for (int ci = wave; ci < 33; ci += 4) {
            const unsigned short* g;
            if (ci < 24) {
                int t = ci >> 3, rb = ci & 7;
                g = wAf + ((size_t)(((m0 >> 4) + rb) * 3 + t) * 16 + kc) * 512 + lane * 8;
            } else {
                int lb = ci - 24;
                g = ftb + (size_t)(l0 + lb * 16 + lr) * 512 + kc * 32 + lq * 8;
            }
            __builtin_amdgcn_global_load_lds((const AS1 void*)g,
                                             (AS3 void*)(smem + ci * 512), 16, 0, 0);
        }
        __syncthreads();
        #pragma unroll
        for (int t = 0; t < 3; ++t) {
            short8 af[4], bf[4];
            #pragma unroll
            for (int fm = 0; fm < 4; ++fm)
                af[fm] = *(const short8*)(smem + ((t * 8 + wm * 4 + fm) << 9) + (lane << 3));
            #pragma unroll
            for (int fn = 0; fn < 4; ++fn) {
                int R = wn * 64 + fn * 16 + lr + t;   // tap-shifted B row
                bf[fn] = *(const short8*)(smem + ((24 + (R >> 4)) << 9) +
                                          ((((lq << 4) | (R & 15))) << 3));
            }
            #pragma unroll
            for (int fm = 0; fm < 4; ++fm)
                #pragma unroll
                for (int fn = 0; fn < 4; ++fn)
                    acc[fm][fn] = __builtin_amdgcn_mfma_f32_16x16x32_bf16(
                        af[fm], bf[fn], acc[fm][fn], 0, 0, 0);
        }
    }
    __syncthreads();
    // epilogue 1: bias + relu -> bf16 htile [l=n][c=cout], row stride 136
    #pragma unroll
    for (int fm = 0; fm < 4; ++fm) {
        int mb = wm * 64 + fm * 16 + lq * 4;
        float cb0 = conv_b[m0 + mb];
        float cb1 = conv_b[m0 + mb + 1];
        float cb2 = conv_b[m0 + mb + 2];
        float cb3 = conv_b[m0 + mb + 3];
        #pragma unroll
        for (int fn = 0; fn < 4; ++fn) {
            int n = wn * 64 + fn * 16 + lr;
            f32x4 v = acc[fm][fn];
            u16x4 pk;
            pk.x = f2bf(fmaxf(v.x + cb0, 0.f));
            pk.y = f2bf(fmaxf(v.y + cb1, 0.f));
            pk.z = f2bf(fmaxf(v.z + cb2, 0.f));
            pk.w = f2bf(fmaxf(v.w + cb3, 0.f));
            *(u16x4*)(smem + n * 136 + mb) = pk;
        }
    }
    __syncthreads();
    // epilogue 2: fused heads. Per wave: 32 l's x 32 j's x K=128 local couts.
    f32x4 hacc[2][2];
    #pragma unroll
    for (int i = 0; i < 2; ++i) {
        hacc[i][0] = (f32x4){0.f, 0.f, 0.f, 0.f};
        hacc[i][1] = (f32x4){0.f, 0.f, 0.f, 0.f};
    }
    const int lbase = wave * 32;
    for (int kk = 0; kk < 4; ++kk) {
        short8 ha[2], hb2[2];
        #pragma unroll
        for (int fm2 = 0; fm2 < 2; ++fm2)
            ha[fm2] = *(const short8*)(smem + (lbase + fm2 * 16 + lr) * 136 + kk * 32 + lq * 8);
        #pragma unroll
        for (int fn = 0; fn < 2; ++fn)
            hb2[fn] = *(const short8*)(hwp + (size_t)(fn * 16 + lr) * 512 + m0 + kk * 32 + lq * 8);
        #pragma unroll
        for (int fm2 = 0; fm2 < 2; ++fm2)
            #pragma unroll
            for (int fn = 0; fn < 2; ++fn)
                hacc[fm2][fn] = __builtin_amdgcn_mfma_f32_16x16x32_bf16(
                    ha[fm2], hb2[fn], hacc[fm2][fn], 0, 0, 0);
    }
    // partials store: part[mblk=by][b][l][j]
    float* pb = part + ((size_t)(blockIdx.y * 4 + b) * 8192) * 18;
    #pragma unroll
    for (int fn = 0; fn < 2; ++fn) {
        int j = fn * 16 + lr;
        if (j >= 18) continue;
        #pragma unroll
        for (int fm2 = 0; fm2 < 2; ++fm2)
            #pragma unroll
            for (int r = 0; r < 4; ++r) {
                int l = l0 + lbase + fm2 * 16 + lq * 4 + r;
                pb[(size_t)l * 18 + j] = hacc[fm2][fn][r];
            }
    }
}

__global__ __launch_bounds__(256) void reduce_kernel(
    const float* __restrict__ part, const float* __restrict__ obj_b,
    const float* __restrict__ reg_b, float* __restrict__ out) {
    unsigned int idx = blockIdx.x * 256 + threadIdx.x;
    if (idx >= 589824u) return;
    unsigned int j = idx % 18u;
    unsigned int t = idx / 18u;
    unsigned int l = t & 8191u;
    unsigned int b = t >> 13;
    float s = 0.f;
    #pragma unroll
    for (int mb = 0; mb < 4; ++mb)
        s += part[((size_t)(mb * 4 + b) * 8192 + l) * 18 + j];
    if (j < 6u) {
        s += obj_b[j];
        out[(size_t)b * 49152 + l * 6 + j] = s;
    } else {
        s += reg_b[j - 6u];
        out[196608u + (size_t)b * 98304 + l * 12 + (j - 6u)] = s;
    }
}

extern "C" void kernel_launch(void* const* d_in, const int* in_sizes, int n_in,
                              void* d_out, int out_size, void* d_ws, size_t ws_size,
                              hipStream_t stream) {
    const float* feat   = (const float*)d_in[0];
    const float* conv_w = (const float*)d_in[1];
    const float* conv_b = (const float*)d_in[2];
    const float* obj_w  = (const float*)d_in[3];
    const float* obj_b  = (const float*)d_in[4];
    const float* reg_w  = (const float*)d_in[5];
    const float* reg_b  = (const float*)d_in[6];
    float* out = (float*)d_out;
    char* ws = (char*)d_ws;
    unsigned short* wAf   = (unsigned short*)(ws);
    unsigned short* hwp   = (unsigned short*)(ws + 1572864);
    unsigned short* featT = (unsigned short*)(ws + 1605632);
    float* part           = (float*)(ws + 35225600);

    prep_transpose_kernel<<<dim3(7440), dim3(256), 0, stream>>>(
        feat, conv_w, obj_w, reg_w, wAf, hwp, featT, out);
    conv_gemm_kernel<<<dim3(64, 4, 4), dim3(256), 0, stream>>>(wAf, featT, conv_b, hwp, part);
    reduce_kernel<<<dim3(2304), dim3(256), 0, stream>>>(part, obj_b, reg_b, out);
}